// Round 1
// baseline (5346.579 us; speedup 1.0000x reference)
//
#include <hip/hip_runtime.h>
#include <hip/hip_bf16.h>

typedef __hip_bfloat16 bf16;
typedef __attribute__((ext_vector_type(4))) float f32x4;
typedef __attribute__((ext_vector_type(8))) short short8;

#define T_STEPS 100
#define BATCH   200
#define BP      256   // padded batch for clean 64-row M tiles
#define NG      4096
#define PLACE_OFF 10240000  // T*B*512

__device__ __forceinline__ void async_copy16(const bf16* gp, bf16* lp) {
    __builtin_amdgcn_global_load_lds((const __attribute__((address_space(1))) void*)gp,
                                     (__attribute__((address_space(3))) void*)lp, 16, 0, 0);
}

// Computes acc[FR][FR] (each f32x4) for C = A * B^T tile at (mBlk,nBlk).
// A: [M x K] row-major bf16, B: [N x K] row-major bf16 (row stride == K).
// Block = 256 threads = 4 waves in 2x2 grid; wave computes (FR*16)x(FR*16).
// Tile is (FR*32) x (FR*32). BK = 64.
template<int FR>
__device__ __forceinline__ void gemm_core(const bf16* __restrict__ A, const bf16* __restrict__ B,
                                          int K, int mBlk, int nBlk,
                                          bf16* As, bf16* Bs, f32x4 (&acc)[FR][FR]) {
    const int tid  = threadIdx.x;
    const int wave = tid >> 6, lane = tid & 63;
    const int waveM = (wave & 1) * (FR * 16);
    const int waveN = (wave >> 1) * (FR * 16);
    const int lrow = lane & 15;
    const int kq   = (lane >> 4) * 8;

    f32x4 zero = {0.f, 0.f, 0.f, 0.f};
#pragma unroll
    for (int mi = 0; mi < FR; ++mi)
#pragma unroll
        for (int ni = 0; ni < FR; ++ni) acc[mi][ni] = zero;

    for (int kb = 0; kb < K; kb += 64) {
        // stage A and B tiles: (FR*32) rows x 64 k each, 16B chunks, lane-contiguous LDS
#pragma unroll
        for (int i = 0; i < FR; ++i) {
            int q   = i * 256 + tid;
            int row = q >> 3, j = q & 7;
            bf16* lp = As + (size_t)(i * 256 + wave * 64) * 8;
            async_copy16(A + (size_t)(mBlk + row) * K + kb + j * 8, lp);
            bf16* lpb = Bs + (size_t)(i * 256 + wave * 64) * 8;
            async_copy16(B + (size_t)(nBlk + row) * K + kb + j * 8, lpb);
        }
        __syncthreads();
#pragma unroll
        for (int kk = 0; kk < 2; ++kk) {
            short8 af[FR], bfr[FR];
#pragma unroll
            for (int mi = 0; mi < FR; ++mi)
                af[mi] = *(const short8*)(As + (waveM + mi * 16 + lrow) * 64 + kk * 32 + kq);
#pragma unroll
            for (int ni = 0; ni < FR; ++ni)
                bfr[ni] = *(const short8*)(Bs + (waveN + ni * 16 + lrow) * 64 + kk * 32 + kq);
#pragma unroll
            for (int mi = 0; mi < FR; ++mi)
#pragma unroll
                for (int ni = 0; ni < FR; ++ni)
                    acc[mi][ni] = __builtin_amdgcn_mfma_f32_16x16x32_bf16(af[mi], bfr[ni], acc[mi][ni], 0, 0, 0);
        }
        __syncthreads();
    }
}

// ---- prep: convert weights to bf16, build concatenated encoder operands ----
__global__ __launch_bounds__(256) void k_prep(const float* __restrict__ image,
                                              const float* __restrict__ init_actv,
                                              const float* __restrict__ Wepc,
                                              const float* __restrict__ Weimg,
                                              const float* __restrict__ Whin,
                                              const float* __restrict__ Wdpc,
                                              const float* __restrict__ Wdimg,
                                              bf16* __restrict__ Wh, bf16* __restrict__ Wdec,
                                              bf16* __restrict__ Benc, bf16* __restrict__ Aenc) {
    const int NWH = 16777216;   // 4096*4096
    const int NWD = 2097152;    // 512*4096
    const int NBE = 4194304;    // 4096*1024
    const int NAE = 262144;     // 256*1024
    const int total = NWH + 2 * NWD + NBE + NAE;
    for (int i = blockIdx.x * blockDim.x + threadIdx.x; i < total; i += gridDim.x * blockDim.x) {
        if (i < NWH) {
            Wh[i] = __float2bfloat16(Whin[i]);
        } else if (i < NWH + NWD) {
            int j = i - NWH;
            Wdec[j] = __float2bfloat16(Wdpc[j]);
        } else if (i < NWH + 2 * NWD) {
            int j = i - NWH - NWD;
            Wdec[NWD + j] = __float2bfloat16(Wdimg[j]);
        } else if (i < NWH + 2 * NWD + NBE) {
            int j = i - NWH - 2 * NWD;
            int g = j >> 10, c = j & 1023;
            float v = (c < 512) ? Wepc[g * 512 + c] : Weimg[g * 512 + (c - 512)];
            Benc[j] = __float2bfloat16(v);
        } else {
            int j = i - NWH - 2 * NWD - NBE;
            int b = j >> 10, c = j & 1023;
            float v = 0.f;
            if (b < BATCH) v = (c < 512) ? init_actv[b * 512 + c] : image[b * 512 + (c - 512)];
            Aenc[j] = __float2bfloat16(v);
        }
    }
}

// ---- h0 = Aenc * Benc^T, K=1024, plain bf16 store ----
__global__ __launch_bounds__(256) void k_h0(const bf16* __restrict__ A, const bf16* __restrict__ B,
                                            bf16* __restrict__ H) {
    __shared__ __align__(16) bf16 As[64 * 64];
    __shared__ __align__(16) bf16 Bs[64 * 64];
    f32x4 acc[2][2];
    int mBlk = blockIdx.y * 64, nBlk = blockIdx.x * 64;
    gemm_core<2>(A, B, 1024, mBlk, nBlk, As, Bs, acc);
    int lane = threadIdx.x & 63, wave = threadIdx.x >> 6;
    int waveM = (wave & 1) * 32, waveN = (wave >> 1) * 32;
#pragma unroll
    for (int mi = 0; mi < 2; ++mi)
#pragma unroll
        for (int r = 0; r < 4; ++r) {
            int row = mBlk + waveM + mi * 16 + (lane >> 4) * 4 + r;
#pragma unroll
            for (int ni = 0; ni < 2; ++ni) {
                int col = nBlk + waveN + ni * 16 + (lane & 15);
                H[(size_t)row * NG + col] = __float2bfloat16(acc[mi][ni][r]);
            }
        }
}

// ---- one recurrence step: Gc = relu(venc_t + Gp * Wh^T) ----
__global__ __launch_bounds__(256) void k_step(const bf16* __restrict__ Gp, const bf16* __restrict__ Wh,
                                              bf16* __restrict__ Gc, const float* __restrict__ vel,
                                              const float* __restrict__ Wv, int t) {
    __shared__ __align__(16) bf16 As[64 * 64];
    __shared__ __align__(16) bf16 Bs[64 * 64];
    f32x4 acc[2][2];
    int mBlk = blockIdx.y * 64, nBlk = blockIdx.x * 64;
    gemm_core<2>(Gp, Wh, NG, mBlk, nBlk, As, Bs, acc);
    int lane = threadIdx.x & 63, wave = threadIdx.x >> 6;
    int waveM = (wave & 1) * 32, waveN = (wave >> 1) * 32;
    float wv0[2], wv1[2];
    int cols[2];
#pragma unroll
    for (int ni = 0; ni < 2; ++ni) {
        cols[ni] = nBlk + waveN + ni * 16 + (lane & 15);
        wv0[ni] = Wv[cols[ni] * 2 + 0];
        wv1[ni] = Wv[cols[ni] * 2 + 1];
    }
#pragma unroll
    for (int mi = 0; mi < 2; ++mi)
#pragma unroll
        for (int r = 0; r < 4; ++r) {
            int row = mBlk + waveM + mi * 16 + (lane >> 4) * 4 + r;
            float v0 = 0.f, v1 = 0.f;
            if (row < BATCH) {
                v0 = vel[(size_t)(t * BATCH + row) * 2 + 0];
                v1 = vel[(size_t)(t * BATCH + row) * 2 + 1];
            }
#pragma unroll
            for (int ni = 0; ni < 2; ++ni) {
                float v = acc[mi][ni][r] + v0 * wv0[ni] + v1 * wv1[ni];
                v = fmaxf(v, 0.f);
                Gc[(size_t)row * NG + cols[ni]] = __float2bfloat16(v);
            }
        }
}

// ---- decode: [25600 x 4096] * Wdec^T[1024 x 4096]; cols<512 -> place, >=512 -> sigmoid image ----
__global__ __launch_bounds__(256) void k_decode(const bf16* __restrict__ G, const bf16* __restrict__ Wd,
                                                float* __restrict__ out) {
    __shared__ __align__(16) bf16 As[128 * 64];
    __shared__ __align__(16) bf16 Bs[128 * 64];
    f32x4 acc[4][4];
    int mBlk = blockIdx.y * 128, nBlk = blockIdx.x * 128;
    gemm_core<4>(G, Wd, NG, mBlk, nBlk, As, Bs, acc);
    int lane = threadIdx.x & 63, wave = threadIdx.x >> 6;
    int waveM = (wave & 1) * 64, waveN = (wave >> 1) * 64;
#pragma unroll
    for (int mi = 0; mi < 4; ++mi)
#pragma unroll
        for (int r = 0; r < 4; ++r) {
            int R = mBlk + waveM + mi * 16 + (lane >> 4) * 4 + r;
            int t = R >> 8, b = R & 255;
            if (b < BATCH) {
                size_t obase = (size_t)(t * BATCH + b) * 512;
#pragma unroll
                for (int ni = 0; ni < 4; ++ni) {
                    int col = nBlk + waveN + ni * 16 + (lane & 15);
                    float v = acc[mi][ni][r];
                    if (col < 512) {
                        out[obase + col] = v;
                    } else {
                        out[PLACE_OFF + obase + (col - 512)] = 1.f / (1.f + __expf(-v));
                    }
                }
            }
        }
}

extern "C" void kernel_launch(void* const* d_in, const int* in_sizes, int n_in,
                              void* d_out, int out_size, void* d_ws, size_t ws_size,
                              hipStream_t stream) {
    const float* image     = (const float*)d_in[0];
    const float* vel       = (const float*)d_in[1];
    const float* init_actv = (const float*)d_in[2];
    const float* Wepc      = (const float*)d_in[3];
    const float* Weimg     = (const float*)d_in[4];
    const float* Wv        = (const float*)d_in[5];
    const float* Whin      = (const float*)d_in[6];
    const float* Wdpc      = (const float*)d_in[7];
    const float* Wdimg     = (const float*)d_in[8];
    float* out = (float*)d_out;

    char* w = (char*)d_ws;
    bf16* Wh   = (bf16*)w; w += (size_t)16777216 * 2;  // 4096x4096
    bf16* Wdec = (bf16*)w; w += (size_t)4194304 * 2;   // 1024x4096
    bf16* Benc = (bf16*)w; w += (size_t)4194304 * 2;   // 4096x1024
    bf16* Aenc = (bf16*)w; w += (size_t)262144 * 2;    // 256x1024
    bf16* H0   = (bf16*)w; w += (size_t)(BP * NG) * 2; // 256x4096
    bf16* Gall = (bf16*)w;                             // 100 x 256 x 4096

    k_prep<<<4096, 256, 0, stream>>>(image, init_actv, Wepc, Weimg, Whin, Wdpc, Wdimg,
                                     Wh, Wdec, Benc, Aenc);
    k_h0<<<dim3(64, 4), 256, 0, stream>>>(Aenc, Benc, H0);
    for (int t = 0; t < T_STEPS; ++t) {
        const bf16* Gp = (t == 0) ? H0 : (Gall + (size_t)(t - 1) * BP * NG);
        k_step<<<dim3(64, 4), 256, 0, stream>>>(Gp, Wh, Gall + (size_t)t * BP * NG, vel, Wv, t);
    }
    k_decode<<<dim3(8, 200), 256, 0, stream>>>(Gall, Wdec, out);
}

// Round 2
// 2883.313 us; speedup vs baseline: 1.8543x; 1.8543x over previous
//
#include <hip/hip_runtime.h>
#include <hip/hip_bf16.h>

typedef __hip_bfloat16 bf16;
typedef __attribute__((ext_vector_type(4))) float f32x4;
typedef __attribute__((ext_vector_type(8))) short short8;

#define T_STEPS 100
#define BATCH   200
#define BP      256
#define NG      4096
#define KCH     512          // K-chunk per split (8 splits)
#define PLACE_OFF 10240000   // T*B*512

__device__ __forceinline__ void async_copy16(const bf16* gp, bf16* lp) {
    __builtin_amdgcn_global_load_lds((const __attribute__((address_space(1))) void*)gp,
                                     (__attribute__((address_space(3))) void*)lp, 16, 0, 0);
}

__device__ __forceinline__ short bf16bits(float x) {
    bf16 h = __float2bfloat16(x);
    return *(short*)&h;
}

// ================= legacy 64x64 core (used only by k_h0, cheap) =================
template<int FR>
__device__ __forceinline__ void gemm_core(const bf16* __restrict__ A, const bf16* __restrict__ B,
                                          int K, int mBlk, int nBlk,
                                          bf16* As, bf16* Bs, f32x4 (&acc)[FR][FR]) {
    const int tid  = threadIdx.x;
    const int wave = tid >> 6, lane = tid & 63;
    const int waveM = (wave & 1) * (FR * 16);
    const int waveN = (wave >> 1) * (FR * 16);
    const int lrow = lane & 15;
    const int kq   = (lane >> 4) * 8;

    f32x4 zero = {0.f, 0.f, 0.f, 0.f};
#pragma unroll
    for (int mi = 0; mi < FR; ++mi)
#pragma unroll
        for (int ni = 0; ni < FR; ++ni) acc[mi][ni] = zero;

    for (int kb = 0; kb < K; kb += 64) {
#pragma unroll
        for (int i = 0; i < FR; ++i) {
            int q   = i * 256 + tid;
            int row = q >> 3, j = q & 7;
            bf16* lp = As + (size_t)(i * 256 + wave * 64) * 8;
            async_copy16(A + (size_t)(mBlk + row) * K + kb + j * 8, lp);
            bf16* lpb = Bs + (size_t)(i * 256 + wave * 64) * 8;
            async_copy16(B + (size_t)(nBlk + row) * K + kb + j * 8, lpb);
        }
        __syncthreads();
#pragma unroll
        for (int kk = 0; kk < 2; ++kk) {
            short8 af[FR], bfr[FR];
#pragma unroll
            for (int mi = 0; mi < FR; ++mi)
                af[mi] = *(const short8*)(As + (waveM + mi * 16 + lrow) * 64 + kk * 32 + kq);
#pragma unroll
            for (int ni = 0; ni < FR; ++ni)
                bfr[ni] = *(const short8*)(Bs + (waveN + ni * 16 + lrow) * 64 + kk * 32 + kq);
#pragma unroll
            for (int mi = 0; mi < FR; ++mi)
#pragma unroll
                for (int ni = 0; ni < FR; ++ni)
                    acc[mi][ni] = __builtin_amdgcn_mfma_f32_16x16x32_bf16(af[mi], bfr[ni], acc[mi][ni], 0, 0, 0);
        }
        __syncthreads();
    }
}

// ================= prep =================
__global__ __launch_bounds__(256) void k_prep(const float* __restrict__ image,
                                              const float* __restrict__ init_actv,
                                              const float* __restrict__ Wepc,
                                              const float* __restrict__ Weimg,
                                              const float* __restrict__ Whin,
                                              const float* __restrict__ Wdpc,
                                              const float* __restrict__ Wdimg,
                                              bf16* __restrict__ Wh, bf16* __restrict__ Wdec,
                                              bf16* __restrict__ Benc, bf16* __restrict__ Aenc) {
    const int NWH = 16777216;
    const int NWD = 2097152;
    const int NBE = 4194304;
    const int NAE = 262144;
    const int total = NWH + 2 * NWD + NBE + NAE;
    for (int i = blockIdx.x * blockDim.x + threadIdx.x; i < total; i += gridDim.x * blockDim.x) {
        if (i < NWH) {
            Wh[i] = __float2bfloat16(Whin[i]);
        } else if (i < NWH + NWD) {
            int j = i - NWH;
            Wdec[j] = __float2bfloat16(Wdpc[j]);
        } else if (i < NWH + 2 * NWD) {
            int j = i - NWH - NWD;
            Wdec[NWD + j] = __float2bfloat16(Wdimg[j]);
        } else if (i < NWH + 2 * NWD + NBE) {
            int j = i - NWH - 2 * NWD;
            int g = j >> 10, c = j & 1023;
            float v = (c < 512) ? Wepc[g * 512 + c] : Weimg[g * 512 + (c - 512)];
            Benc[j] = __float2bfloat16(v);
        } else {
            int j = i - NWH - 2 * NWD - NBE;
            int b = j >> 10, c = j & 1023;
            float v = 0.f;
            if (b < BATCH) v = (c < 512) ? init_actv[b * 512 + c] : image[b * 512 + (c - 512)];
            Aenc[j] = __float2bfloat16(v);
        }
    }
}

// ================= h0 =================
__global__ __launch_bounds__(256) void k_h0(const bf16* __restrict__ A, const bf16* __restrict__ B,
                                            bf16* __restrict__ H) {
    __shared__ __align__(16) bf16 As[64 * 64];
    __shared__ __align__(16) bf16 Bs[64 * 64];
    f32x4 acc[2][2];
    int mBlk = blockIdx.y * 64, nBlk = blockIdx.x * 64;
    gemm_core<2>(A, B, 1024, mBlk, nBlk, As, Bs, acc);
    int lane = threadIdx.x & 63, wave = threadIdx.x >> 6;
    int waveM = (wave & 1) * 32, waveN = (wave >> 1) * 32;
#pragma unroll
    for (int mi = 0; mi < 2; ++mi)
#pragma unroll
        for (int r = 0; r < 4; ++r) {
            int row = mBlk + waveM + mi * 16 + (lane >> 4) * 4 + r;
#pragma unroll
            for (int ni = 0; ni < 2; ++ni) {
                int col = nBlk + waveN + ni * 16 + (lane & 15);
                H[(size_t)row * NG + col] = __float2bfloat16(acc[mi][ni][r]);
            }
        }
}

// ================= step GEMM: partial[s] = Gp * Wh^T over K-chunk s =================
// 512 blocks: s = blockIdx.x & 7 (XCD-affine), colblk = blockIdx.x >> 3.
// Block tile: 256 rows x 64 cols, K = 512. 4 waves, wave w = rows [64w, 64w+64).
__global__ __launch_bounds__(256, 2) void k_gstep(const bf16* __restrict__ Gp,
                                                  const bf16* __restrict__ Wh,
                                                  float* __restrict__ partial) {
    __shared__ __align__(16) bf16 As[256 * 64];   // 32 KB
    __shared__ __align__(16) bf16 Bs[64 * 64];    // 8 KB
    const int tid = threadIdx.x;
    const int wave = tid >> 6, lane = tid & 63;
    const int lrow = lane & 15;
    const int kq = lane >> 4;
    const int s = blockIdx.x & 7;
    const int colbase = (blockIdx.x >> 3) * 64;
    const int kbase = s * KCH;

    f32x4 acc[4][4];
    f32x4 zero = {0.f, 0.f, 0.f, 0.f};
#pragma unroll
    for (int mi = 0; mi < 4; ++mi)
#pragma unroll
        for (int ni = 0; ni < 4; ++ni) acc[mi][ni] = zero;

    for (int kb = 0; kb < KCH; kb += 64) {
#pragma unroll
        for (int i = 0; i < 8; ++i) {           // A: 256 rows x 8 chunks
            int q = i * 256 + tid;
            int row = q >> 3, j = q & 7;
            int jsrc = j ^ (row & 7);           // xor-swizzle the SOURCE k-chunk
            async_copy16(Gp + (size_t)row * NG + kbase + kb + jsrc * 8, As + q * 8);
        }
#pragma unroll
        for (int i = 0; i < 2; ++i) {           // B: 64 cols x 8 chunks
            int q = i * 256 + tid;
            int row = q >> 3, j = q & 7;
            int jsrc = j ^ (row & 7);
            async_copy16(Wh + (size_t)(colbase + row) * NG + kbase + kb + jsrc * 8, Bs + q * 8);
        }
        __syncthreads();
#pragma unroll
        for (int kk = 0; kk < 2; ++kk) {
            int c = kk * 4 + kq;
            short8 af[4], bfv[4];
#pragma unroll
            for (int mi = 0; mi < 4; ++mi) {
                int r = wave * 64 + mi * 16 + lrow;
                af[mi] = *(const short8*)(As + r * 64 + ((c ^ (r & 7)) * 8));
            }
#pragma unroll
            for (int ni = 0; ni < 4; ++ni) {
                int cl = ni * 16 + lrow;
                bfv[ni] = *(const short8*)(Bs + cl * 64 + ((c ^ (cl & 7)) * 8));
            }
#pragma unroll
            for (int mi = 0; mi < 4; ++mi)
#pragma unroll
                for (int ni = 0; ni < 4; ++ni)
                    acc[mi][ni] = __builtin_amdgcn_mfma_f32_16x16x32_bf16(af[mi], bfv[ni], acc[mi][ni], 0, 0, 0);
        }
        __syncthreads();
    }

    float* pbase = partial + (size_t)s * BP * NG;
#pragma unroll
    for (int mi = 0; mi < 4; ++mi)
#pragma unroll
        for (int r = 0; r < 4; ++r) {
            int row = wave * 64 + mi * 16 + (lane >> 4) * 4 + r;
#pragma unroll
            for (int ni = 0; ni < 4; ++ni) {
                int col = colbase + ni * 16 + lrow;
                pbase[(size_t)row * NG + col] = acc[mi][ni][r];
            }
        }
}

// ================= reduce: Gc = relu(sum_s partial + venc) =================
// 512 blocks: row = b>>1, col half = b&1. 256 threads x 8 cols.
__global__ __launch_bounds__(256) void k_reduce(const float* __restrict__ partial,
                                                const float* __restrict__ vel,
                                                const float* __restrict__ Wv,
                                                bf16* __restrict__ Gc, int t) {
    const int b = blockIdx.x;
    const int row = b >> 1;
    const int cbase = (b & 1) * 2048 + threadIdx.x * 8;
    float v0 = 0.f, v1 = 0.f;
    if (row < BATCH) {
        v0 = vel[(size_t)(t * BATCH + row) * 2 + 0];
        v1 = vel[(size_t)(t * BATCH + row) * 2 + 1];
    }
    f32x4 sum0 = {0.f, 0.f, 0.f, 0.f}, sum1 = {0.f, 0.f, 0.f, 0.f};
#pragma unroll
    for (int s = 0; s < 8; ++s) {
        const float* p = partial + (size_t)(s * BP + row) * NG + cbase;
        sum0 += *(const f32x4*)p;
        sum1 += *(const f32x4*)(p + 4);
    }
    const f32x4* wp = (const f32x4*)(Wv + (size_t)cbase * 2);
    f32x4 w0 = wp[0], w1 = wp[1], w2 = wp[2], w3 = wp[3];
    float o[8];
    o[0] = sum0[0] + v0 * w0[0] + v1 * w0[1];
    o[1] = sum0[1] + v0 * w0[2] + v1 * w0[3];
    o[2] = sum0[2] + v0 * w1[0] + v1 * w1[1];
    o[3] = sum0[3] + v0 * w1[2] + v1 * w1[3];
    o[4] = sum1[0] + v0 * w2[0] + v1 * w2[1];
    o[5] = sum1[1] + v0 * w2[2] + v1 * w2[3];
    o[6] = sum1[2] + v0 * w3[0] + v1 * w3[1];
    o[7] = sum1[3] + v0 * w3[2] + v1 * w3[3];
    short8 ov;
#pragma unroll
    for (int j = 0; j < 8; ++j) ov[j] = bf16bits(fmaxf(o[j], 0.f));
    *(short8*)(Gc + (size_t)row * NG + cbase) = ov;
}

// ================= decode: 128x512 tile, 512 thr (8 waves 2x4), kb=32 =================
__global__ __launch_bounds__(512, 2) void k_decode(const bf16* __restrict__ G,
                                                   const bf16* __restrict__ Wd,
                                                   float* __restrict__ out) {
    __shared__ __align__(16) bf16 As[128 * 32];   // 8 KB
    __shared__ __align__(16) bf16 Bs[512 * 32];   // 32 KB
    const int tid = threadIdx.x;
    const int wave = tid >> 6, lane = tid & 63;
    const int lrow = lane & 15;
    const int kq = lane >> 4;
    const int mBlk = blockIdx.y * 128;
    const int nBase = blockIdx.x * 512;
    const int waveM = (wave & 1) * 64;
    const int waveN = (wave >> 1) * 128;

    f32x4 acc[4][8];
    f32x4 zero = {0.f, 0.f, 0.f, 0.f};
#pragma unroll
    for (int mi = 0; mi < 4; ++mi)
#pragma unroll
        for (int ni = 0; ni < 8; ++ni) acc[mi][ni] = zero;

    for (int kb = 0; kb < NG; kb += 32) {
        {
            int q = tid;                         // A: 128 rows x 4 chunks
            int row = q >> 2, j = q & 3;
            int jsrc = j ^ (row & 3);
            async_copy16(G + (size_t)(mBlk + row) * NG + kb + jsrc * 8, As + q * 8);
        }
#pragma unroll
        for (int i = 0; i < 4; ++i) {            // B: 512 cols x 4 chunks
            int q = i * 512 + tid;
            int col = q >> 2, j = q & 3;
            int jsrc = j ^ (col & 3);
            async_copy16(Wd + (size_t)(nBase + col) * NG + kb + jsrc * 8, Bs + q * 8);
        }
        __syncthreads();
        short8 af[4], bfv[8];
#pragma unroll
        for (int mi = 0; mi < 4; ++mi) {
            int r = waveM + mi * 16 + lrow;
            af[mi] = *(const short8*)(As + r * 32 + ((kq ^ (r & 3)) * 8));
        }
#pragma unroll
        for (int ni = 0; ni < 8; ++ni) {
            int cl = waveN + ni * 16 + lrow;
            bfv[ni] = *(const short8*)(Bs + cl * 32 + ((kq ^ (cl & 3)) * 8));
        }
#pragma unroll
        for (int mi = 0; mi < 4; ++mi)
#pragma unroll
            for (int ni = 0; ni < 8; ++ni)
                acc[mi][ni] = __builtin_amdgcn_mfma_f32_16x16x32_bf16(af[mi], bfv[ni], acc[mi][ni], 0, 0, 0);
        __syncthreads();
    }

#pragma unroll
    for (int mi = 0; mi < 4; ++mi)
#pragma unroll
        for (int r = 0; r < 4; ++r) {
            int R = mBlk + waveM + mi * 16 + (lane >> 4) * 4 + r;
            int t = R >> 8, bb = R & 255;
            if (bb < BATCH) {
                size_t obase = (size_t)(t * BATCH + bb) * 512;
#pragma unroll
                for (int ni = 0; ni < 8; ++ni) {
                    int col = nBase + waveN + ni * 16 + lrow;
                    float v = acc[mi][ni][r];
                    if (col < 512) {
                        out[obase + col] = v;
                    } else {
                        out[PLACE_OFF + obase + (col - 512)] = 1.f / (1.f + __expf(-v));
                    }
                }
            }
        }
}

extern "C" void kernel_launch(void* const* d_in, const int* in_sizes, int n_in,
                              void* d_out, int out_size, void* d_ws, size_t ws_size,
                              hipStream_t stream) {
    const float* image     = (const float*)d_in[0];
    const float* vel       = (const float*)d_in[1];
    const float* init_actv = (const float*)d_in[2];
    const float* Wepc      = (const float*)d_in[3];
    const float* Weimg     = (const float*)d_in[4];
    const float* Wv        = (const float*)d_in[5];
    const float* Whin      = (const float*)d_in[6];
    const float* Wdpc      = (const float*)d_in[7];
    const float* Wdimg     = (const float*)d_in[8];
    float* out = (float*)d_out;

    char* w = (char*)d_ws;
    bf16*  Wh      = (bf16*)w;  w += (size_t)16777216 * 2;   // 4096x4096
    bf16*  Wdec    = (bf16*)w;  w += (size_t)4194304 * 2;    // 1024x4096
    bf16*  Benc    = (bf16*)w;  w += (size_t)4194304 * 2;    // 4096x1024
    bf16*  Aenc    = (bf16*)w;  w += (size_t)262144 * 2;     // 256x1024
    bf16*  H0      = (bf16*)w;  w += (size_t)(BP * NG) * 2;  // 256x4096
    float* partial = (float*)w; w += (size_t)8 * BP * NG * 4; // 8x256x4096 fp32
    bf16*  Gall    = (bf16*)w;                                // 100x256x4096

    k_prep<<<4096, 256, 0, stream>>>(image, init_actv, Wepc, Weimg, Whin, Wdpc, Wdimg,
                                     Wh, Wdec, Benc, Aenc);
    k_h0<<<dim3(64, 4), 256, 0, stream>>>(Aenc, Benc, H0);
    for (int t = 0; t < T_STEPS; ++t) {
        const bf16* Gp = (t == 0) ? H0 : (Gall + (size_t)(t - 1) * BP * NG);
        k_gstep<<<512, 256, 0, stream>>>(Gp, Wh, partial);
        k_reduce<<<512, 256, 0, stream>>>(partial, vel, Wv, Gall + (size_t)t * BP * NG, t);
    }
    k_decode<<<dim3(2, 200), 512, 0, stream>>>(Gall, Wdec, out);
}